// Round 1
// baseline (741.875 us; speedup 1.0000x reference)
//
#include <hip/hip_runtime.h>

typedef unsigned short u16;
typedef __bf16 bf16x8 __attribute__((ext_vector_type(8)));
typedef float f32x4 __attribute__((ext_vector_type(4)));

#define MFMA(a, b, c) __builtin_amdgcn_mfma_f32_16x16x32_bf16(a, b, c, 0, 0, 0)

static __device__ __forceinline__ u16 f2bf(float f) {
  unsigned u = __float_as_uint(f);
  u = u + 0x7FFFu + ((u >> 16) & 1u);   // round-to-nearest-even
  return (u16)(u >> 16);
}

static __device__ __forceinline__ f32x4 fzero() {
  f32x4 z; z[0] = 0.f; z[1] = 0.f; z[2] = 0.f; z[3] = 0.f; return z;
}

// ---- kernel 0: convert qkv_w (196608) + proj_w (65536) fp32 -> bf16 into ws ----
__global__ void cvt_w(const float* __restrict__ qw, const float* __restrict__ pw,
                      u16* __restrict__ o) {
  int i = blockIdx.x * 256 + threadIdx.x;      // grid covers 262144 exactly
  float v = (i < 196608) ? qw[i] : pw[i - 196608];
  o[i] = f2bf(v);
}

// ---- fused window attention: one window per block, 4 waves ----
__global__ __launch_bounds__(256, 2) void swin(
    const float* __restrict__ x, const u16* __restrict__ wqkv,
    const u16* __restrict__ wproj, const float* __restrict__ pb,
    const float* __restrict__ bias, float* __restrict__ out) {

  __shared__ u16 Xs[64 * 264];          // 33792 B; x window (bf16); later aliased as Os
  __shared__ u16 QK[2][2][64 * 40];     // 20480 B; [head_local][q/k][tok*40+d]; P overlays
  __shared__ u16 Vt[2][32 * 72];        // 9216 B;  [head_local][d*72+tok]

  const int tid  = threadIdx.x;
  const int wv   = tid >> 6;
  const int lane = tid & 63;
  const int l15  = lane & 15;
  const int quad = lane >> 4;

  const int w  = blockIdx.x;            // 4096 windows
  const int bb = w >> 10;
  const int wh = (w >> 5) & 31;
  const int ww = w & 31;

  // ---- stage x window -> bf16 LDS ----
  {
    const float* xb = x + ((size_t)bb << 24);
    #pragma unroll
    for (int i = 0; i < 16; ++i) {
      int flat = i * 256 + tid;          // 0..4095 float4s
      int t  = flat >> 6;                // token 0..63
      int c4 = flat & 63;                // float4 within token
      int row = wh * 8 + (t >> 3), col = ww * 8 + (t & 7);
      const float4 v = *(const float4*)(xb + ((size_t)(row * 256 + col) << 8) + c4 * 4);
      unsigned p0 = (unsigned)f2bf(v.x) | ((unsigned)f2bf(v.y) << 16);
      unsigned p1 = (unsigned)f2bf(v.z) | ((unsigned)f2bf(v.w) << 16);
      *(uint2*)&Xs[t * 264 + c4 * 4] = make_uint2(p0, p1);
    }
  }
  __syncthreads();

  const float scale = 0.17677669529663687f;   // 1/sqrt(32)
  unsigned opk[4][8];                          // packed-bf16 O fragments per slot

  #pragma unroll
  for (int s = 0; s < 4; ++s) {
    // ---------- QKV GEMM for heads 2s, 2s+1 (wave computes N-tiles 3w..3w+2 of 12) ----------
    {
      f32x4 acc[3][4];
      #pragma unroll
      for (int a = 0; a < 3; ++a)
        #pragma unroll
        for (int m = 0; m < 4; ++m) acc[a][m] = fzero();

      #pragma unroll
      for (int kk = 0; kk < 8; ++kk) {
        bf16x8 af[4];
        #pragma unroll
        for (int m = 0; m < 4; ++m)
          af[m] = *(const bf16x8*)&Xs[(m * 16 + l15) * 264 + kk * 32 + quad * 8];
        #pragma unroll
        for (int nt = 0; nt < 3; ++nt) {
          int j = wv * 3 + nt;
          int hl = j / 6, r = j % 6, ty = r >> 1, sub = r & 1;
          int d = ty * 256 + (2 * s + hl) * 32 + sub * 16;   // global qkv dim base
          bf16x8 bf = *(const bf16x8*)(wqkv + (size_t)(d + l15) * 256 + kk * 32 + quad * 8);
          #pragma unroll
          for (int m = 0; m < 4; ++m) acc[nt][m] = MFMA(af[m], bf, acc[nt][m]);
        }
      }
      // write results to Qs/Ks (tok-major) or Vt (transposed)
      #pragma unroll
      for (int nt = 0; nt < 3; ++nt) {
        int j = wv * 3 + nt;
        int hl = j / 6, r = j % 6, ty = r >> 1, sub = r & 1;
        int dl = sub * 16 + l15;
        #pragma unroll
        for (int m = 0; m < 4; ++m) {
          if (ty == 2) {
            int t0 = m * 16 + quad * 4;
            unsigned p0 = (unsigned)f2bf(acc[nt][m][0]) | ((unsigned)f2bf(acc[nt][m][1]) << 16);
            unsigned p1 = (unsigned)f2bf(acc[nt][m][2]) | ((unsigned)f2bf(acc[nt][m][3]) << 16);
            *(uint2*)&Vt[hl][dl * 72 + t0] = make_uint2(p0, p1);
          } else {
            #pragma unroll
            for (int e = 0; e < 4; ++e) {
              int t = m * 16 + quad * 4 + e;
              QK[hl][ty][t * 40 + dl] = f2bf(acc[nt][m][e]);
            }
          }
        }
      }
    }
    __syncthreads();

    // ---------- S = (Q*scale) K^T + bias ; softmax ----------
    const int hl = wv >> 1, half = wv & 1;
    const int h  = 2 * s + hl;
    float sb[2][4][4];
    {
      f32x4 sacc[2][4];
      #pragma unroll
      for (int m = 0; m < 2; ++m)
        #pragma unroll
        for (int n = 0; n < 4; ++n) sacc[m][n] = fzero();
      bf16x8 qa[2];
      #pragma unroll
      for (int m = 0; m < 2; ++m) {
        int tq = (2 * half + m) * 16 + l15;
        qa[m] = *(const bf16x8*)&QK[hl][0][tq * 40 + quad * 8];
      }
      #pragma unroll
      for (int n = 0; n < 4; ++n) {
        int tk = n * 16 + l15;
        bf16x8 kb = *(const bf16x8*)&QK[hl][1][tk * 40 + quad * 8];
        #pragma unroll
        for (int m = 0; m < 2; ++m) sacc[m][n] = MFMA(qa[m], kb, sacc[m][n]);
      }
      const float* bh = bias + h * 4096;
      #pragma unroll
      for (int m = 0; m < 2; ++m)
        #pragma unroll
        for (int n = 0; n < 4; ++n)
          #pragma unroll
          for (int e = 0; e < 4; ++e) {
            int tq = (2 * half + m) * 16 + quad * 4 + e;
            int tk = n * 16 + l15;
            sb[m][n][e] = sacc[m][n][e] * scale + bh[tq * 64 + tk];
          }
    }
    float rinv[2][4];
    #pragma unroll
    for (int m = 0; m < 2; ++m)
      #pragma unroll
      for (int e = 0; e < 4; ++e) {
        float mx = sb[m][0][e];
        #pragma unroll
        for (int n = 1; n < 4; ++n) mx = fmaxf(mx, sb[m][n][e]);
        #pragma unroll
        for (int dd = 1; dd < 16; dd <<= 1) mx = fmaxf(mx, __shfl_xor(mx, dd, 64));
        float sum = 0.f;
        #pragma unroll
        for (int n = 0; n < 4; ++n) {
          float p = __expf(sb[m][n][e] - mx);
          sb[m][n][e] = p; sum += p;
        }
        #pragma unroll
        for (int dd = 1; dd < 16; dd <<= 1) sum += __shfl_xor(sum, dd, 64);
        rinv[m][e] = 1.0f / sum;
      }
    __syncthreads();   // Q/K reads done everywhere before P overlays them

    u16* Ps = &QK[0][0][0] + hl * 4608;   // [tok_q*72 + tok_k]
    #pragma unroll
    for (int m = 0; m < 2; ++m)
      #pragma unroll
      for (int n = 0; n < 4; ++n)
        #pragma unroll
        for (int e = 0; e < 4; ++e) {
          int tq = (2 * half + m) * 16 + quad * 4 + e;
          Ps[tq * 72 + n * 16 + l15] = f2bf(sb[m][n][e]);
        }
    __syncthreads();

    // ---------- O = P V (normalize by rinv) ----------
    {
      f32x4 oacc[2][2];
      #pragma unroll
      for (int m = 0; m < 2; ++m)
        #pragma unroll
        for (int n = 0; n < 2; ++n) oacc[m][n] = fzero();
      #pragma unroll
      for (int kk = 0; kk < 2; ++kk) {
        bf16x8 pa[2];
        #pragma unroll
        for (int m = 0; m < 2; ++m) {
          int tq = (2 * half + m) * 16 + l15;
          pa[m] = *(const bf16x8*)&Ps[tq * 72 + kk * 32 + quad * 8];
        }
        #pragma unroll
        for (int n = 0; n < 2; ++n) {
          bf16x8 vb = *(const bf16x8*)&Vt[hl][(n * 16 + l15) * 72 + kk * 32 + quad * 8];
          #pragma unroll
          for (int m = 0; m < 2; ++m) oacc[m][n] = MFMA(pa[m], vb, oacc[m][n]);
        }
      }
      #pragma unroll
      for (int m = 0; m < 2; ++m)
        #pragma unroll
        for (int n = 0; n < 2; ++n) {
          f32x4 v = oacc[m][n];
          opk[s][(m * 2 + n) * 2 + 0] =
              (unsigned)f2bf(v[0] * rinv[m][0]) | ((unsigned)f2bf(v[1] * rinv[m][1]) << 16);
          opk[s][(m * 2 + n) * 2 + 1] =
              (unsigned)f2bf(v[2] * rinv[m][2]) | ((unsigned)f2bf(v[3] * rinv[m][3]) << 16);
        }
    }
    __syncthreads();   // P/Vt reads done before next slot's QKV writes
  }

  // ---- write O fragments into Os (aliases Xs; Xs dead after last slot's QKV) ----
  u16* Os = Xs;
  #pragma unroll
  for (int s = 0; s < 4; ++s) {
    int h = 2 * s + (wv >> 1);
    #pragma unroll
    for (int m = 0; m < 2; ++m)
      #pragma unroll
      for (int n = 0; n < 2; ++n) {
        unsigned p0 = opk[s][(m * 2 + n) * 2 + 0];
        unsigned p1 = opk[s][(m * 2 + n) * 2 + 1];
        int ch = h * 32 + n * 16 + l15;
        int t0 = (2 * (wv & 1) + m) * 16 + quad * 4;
        Os[(t0 + 0) * 264 + ch] = (u16)(p0 & 0xFFFF);
        Os[(t0 + 1) * 264 + ch] = (u16)(p0 >> 16);
        Os[(t0 + 2) * 264 + ch] = (u16)(p1 & 0xFFFF);
        Os[(t0 + 3) * 264 + ch] = (u16)(p1 >> 16);
      }
  }
  __syncthreads();

  // ---- proj GEMM + bias, store fp32 with window->spatial scatter ----
  {
    f32x4 pacc[4][4];
    #pragma unroll
    for (int m = 0; m < 4; ++m)
      #pragma unroll
      for (int n = 0; n < 4; ++n) pacc[m][n] = fzero();
    const int n0 = wv * 64;
    #pragma unroll
    for (int kk = 0; kk < 8; ++kk) {
      bf16x8 af[4];
      #pragma unroll
      for (int m = 0; m < 4; ++m)
        af[m] = *(const bf16x8*)&Os[(m * 16 + l15) * 264 + kk * 32 + quad * 8];
      #pragma unroll
      for (int n = 0; n < 4; ++n) {
        bf16x8 bf = *(const bf16x8*)(wproj + (size_t)(n0 + n * 16 + l15) * 256 + kk * 32 + quad * 8);
        #pragma unroll
        for (int m = 0; m < 4; ++m) pacc[m][n] = MFMA(af[m], bf, pacc[m][n]);
      }
    }
    float* ob = out + ((size_t)bb << 24);
    #pragma unroll
    for (int n = 0; n < 4; ++n) {
      float bv = pb[n0 + n * 16 + l15];
      #pragma unroll
      for (int m = 0; m < 4; ++m)
        #pragma unroll
        for (int e = 0; e < 4; ++e) {
          int t = m * 16 + quad * 4 + e;
          int row = wh * 8 + (t >> 3), col = ww * 8 + (t & 7);
          ob[((size_t)(row * 256 + col) << 8) + n0 + n * 16 + l15] = pacc[m][n][e] + bv;
        }
    }
  }
}

extern "C" void kernel_launch(void* const* d_in, const int* in_sizes, int n_in,
                              void* d_out, int out_size, void* d_ws, size_t ws_size,
                              hipStream_t stream) {
  const float* x  = (const float*)d_in[0];
  const float* qw = (const float*)d_in[1];
  const float* pw = (const float*)d_in[2];
  const float* pb = (const float*)d_in[3];
  const float* bs = (const float*)d_in[4];
  u16* wbf = (u16*)d_ws;                 // 262144 bf16 = 512 KB of ws

  cvt_w<<<1024, 256, 0, stream>>>(qw, pw, wbf);
  swin<<<4096, 256, 0, stream>>>(x, wbf, wbf + 196608, pb, bs, (float*)d_out);
}